// Round 14
// baseline (95.811 us; speedup 1.0000x reference)
//
#include <hip/hip_runtime.h>
#include <hip/hip_bf16.h>
#include <math.h>

#define TOK 16384
#define HDIM 2048
#define NE 64
#define NB 4
#define KTOP 8
#define KC 64
#define NC (HDIM / KC)   // 32 global 64-k chunks (wpk layout)
#define NSL 8            // K-slices (k1)
#define TT 256           // tokens per k1 block
#define XCH 16           // tokens per k1 X-chunk
#define NXC (TT / XCH)   // 16 X-chunks per block
#define BTF 32           // fallback tokens/block

typedef __attribute__((ext_vector_type(8))) __bf16 bf16x8;
typedef __attribute__((ext_vector_type(4))) float f32x4;
typedef unsigned int uint;

__device__ __forceinline__ uint asu(float f) { union { float f; uint u; } c; c.f = f; return c.u; }
__device__ __forceinline__ float asf(uint u) { union { uint u; float f; } c; c.u = u; return c.f; }

// Exact 3-way bf16 split: h+m+l == x bitwise (8 mantissa bits per plane).
__device__ __forceinline__ void split3(float v, uint& h, uint& m, uint& l) {
  uint u = asu(v);
  h = u & 0xffff0000u;
  float d = v - asf(h);
  m = asu(d) & 0xffff0000u;
  float d2 = d - asf(m);
  l = asu(d2);
}

// 8 floats (one fragment k-slot) -> 3 bf16x8 planes, in-register.
__device__ __forceinline__ void split8(float4 a, float4 b,
                                       bf16x8& h8, bf16x8& m8, bf16x8& l8) {
  union { uint4 u; bf16x8 v; } H, M, L;
  uint h0, m0, l0, h1, m1, l1;
  split3(a.x, h0, m0, l0); split3(a.y, h1, m1, l1);
  H.u.x = (h0 >> 16) | (h1 & 0xffff0000u);
  M.u.x = (m0 >> 16) | (m1 & 0xffff0000u);
  L.u.x = (l0 >> 16) | (l1 & 0xffff0000u);
  split3(a.z, h0, m0, l0); split3(a.w, h1, m1, l1);
  H.u.y = (h0 >> 16) | (h1 & 0xffff0000u);
  M.u.y = (m0 >> 16) | (m1 & 0xffff0000u);
  L.u.y = (l0 >> 16) | (l1 & 0xffff0000u);
  split3(b.x, h0, m0, l0); split3(b.y, h1, m1, l1);
  H.u.z = (h0 >> 16) | (h1 & 0xffff0000u);
  M.u.z = (m0 >> 16) | (m1 & 0xffff0000u);
  L.u.z = (l0 >> 16) | (l1 & 0xffff0000u);
  split3(b.z, h0, m0, l0); split3(b.w, h1, m1, l1);
  H.u.w = (h0 >> 16) | (h1 & 0xffff0000u);
  M.u.w = (m0 >> 16) | (m1 & 0xffff0000u);
  L.u.w = (l0 >> 16) | (l1 & 0xffff0000u);
  h8 = H.v; m8 = M.v; l8 = L.v;
}

__device__ __forceinline__ void gl_lds16(const void* g, void* l) {
  __builtin_amdgcn_global_load_lds(
      (const __attribute__((address_space(1))) void*)g,
      (__attribute__((address_space(3))) void*)l, 16, 0, 0);
}

// ---------------------------------------------------------------------------
// wsplit: pack W into 16x16x32 B-fragment order, 3 exact bf16 planes; zero
// stats (528 floats).  byte = c*24576 + ks*12288 + half*6144 + f2*3072
//                           + plane*1024 + lane*16
// ---------------------------------------------------------------------------
__global__ __launch_bounds__(256) void wsplit(const float* __restrict__ w,
                                              char* __restrict__ wpk,
                                              float* __restrict__ stats) {
  if (blockIdx.x == 0 && threadIdx.x < 132) {
    *(float4*)(stats + threadIdx.x * 4) = make_float4(0.f, 0.f, 0.f, 0.f);
  }
  int t = blockIdx.x * 256 + threadIdx.x;    // 16384 threads
  int lane = t & 63;
  int f2 = (t >> 6) & 1, half = (t >> 7) & 1, ks = (t >> 8) & 1, c = t >> 9;
  int e = half * 32 + f2 * 16 + (lane & 15);
  int k = c * 64 + ks * 32 + ((lane >> 4) << 3);
  const float* p = w + (size_t)e * HDIM + k;
  bf16x8 h8, m8, l8;
  split8(*(const float4*)p, *(const float4*)(p + 4), h8, m8, l8);
  union { bf16x8 v; uint4 u; } H, M, L;
  H.v = h8; M.v = m8; L.v = l8;
  size_t base = (size_t)c * 24576 + (size_t)ks * 12288 + (size_t)half * 6144
              + (size_t)f2 * 3072 + (size_t)lane * 16;
  *(uint4*)(wpk + base) = H.u;
  *(uint4*)(wpk + base + 1024) = M.u;
  *(uint4*)(wpk + base + 2048) = L.u;
}

// ---------------------------------------------------------------------------
// k1: GEMM partials, W PERSISTENT IN REGISTERS (no W staging in the K-loop).
// Grid 512 = 8 K-slices x 64 token-tiles (TT=256); 512 thr (8 waves),
// 2 blocks/CU (LDS 65 KB, VGPR capped via launch_bounds).
// Wave (kq = wid>>1, eh = wid&1): owns global chunk slice*4+kq, eh expert
// half -> 12 bf16x8 W frags = 48 VGPR loaded once from L2.
// K-loop stages ONLY X (16 KB/chunk) via gl_lds tri-buffer, counted vmcnt(4)
// (2-chunk latency cover). Per chunk: 24 MFMA/wave -> scq -> 4-way k-merge
// (waves 0-3) -> plain store to part[t][slice][e] (block-exclusive lines,
// deterministic, NO atomics).
// ---------------------------------------------------------------------------
__global__ __launch_bounds__(512, 4) void gate_k1(const float* __restrict__ x,
                                                  const char* __restrict__ wpk,
                                                  float* __restrict__ part) {
  __shared__ __align__(16) char xlds[3 * 16384];
  __shared__ float scq[4][XCH][68];

  const int tid = threadIdx.x;
  const int bid = blockIdx.x;
  const int slice = bid & 7;
  const int tile = bid >> 3;            // 0..63
  const int t0 = tile * TT;
  const int k0 = slice * 256;
  const int lane = tid & 63;
  const int wid = tid >> 6;             // 0..7
  const int eh = wid & 1;
  const int kq = wid >> 1;              // 0..3

  // W fragments -> registers (once). Global chunk cg = slice*4 + kq.
  bf16x8 Wf[2][2][3];                   // [ks][f2][plane]
  {
    const char* wb = wpk + (size_t)(slice * 4 + kq) * 24576 + eh * 6144
                   + (size_t)lane * 16;
#pragma unroll
    for (int ks = 0; ks < 2; ++ks)
#pragma unroll
      for (int f2 = 0; f2 < 2; ++f2)
#pragma unroll
        for (int pl = 0; pl < 3; ++pl)
          Wf[ks][f2][pl] = *(const bf16x8*)(wb + ks * 12288 + f2 * 3072 + pl * 1024);
  }

  // X staging (m173): slot s = r*512+tid = ks(3b)|q(1b)|ln(6b); per-lane
  // swizzled SOURCE, wave-uniform dest + lane*16.
  const char* xsg[2];
  int xdo_[2];
#pragma unroll
  for (int r = 0; r < 2; ++r) {
    int s = r * 512 + tid;
    int sks = s >> 7, sq = (s >> 6) & 1, ln = s & 63;
    xsg[r] = (const char*)(x + (size_t)(t0 + (ln & 15)) * HDIM + k0
                           + sks * 32 + ((ln >> 4) << 3) + sq * 4);
    xdo_[r] = (r * 512 + wid * 64) * 16;
  }

#define STAGE(cc)                                                          \
  {                                                                        \
    char* xd = xlds + ((cc) % 3) * 16384;                                  \
    _Pragma("unroll")                                                      \
    for (int r = 0; r < 2; ++r)                                            \
      gl_lds16(xsg[r] + (size_t)(cc) * (XCH * HDIM * 4), xd + xdo_[r]);    \
  }

  STAGE(0);
  STAGE(1);

#pragma unroll 1
  for (int cc = 0; cc < NXC; ++cc) {
    if (cc + 2 < NXC) STAGE(cc + 2);    // keep 2 chunks in flight
    if (cc + 2 < NXC)      { asm volatile("s_waitcnt vmcnt(4)" ::: "memory"); }
    else if (cc + 1 < NXC) { asm volatile("s_waitcnt vmcnt(2)" ::: "memory"); }
    else                   { asm volatile("s_waitcnt vmcnt(0)" ::: "memory"); }
    __builtin_amdgcn_s_barrier();
    asm volatile("" ::: "memory");

    f32x4 acc[2] = {{0.f, 0.f, 0.f, 0.f}, {0.f, 0.f, 0.f, 0.f}};
    const char* xb = xlds + (cc % 3) * 16384;
#pragma unroll
    for (int ks = 0; ks < 2; ++ks) {
      const char* xk = xb + (kq * 2 + ks) * 2048;
      float4 X0 = *(const float4*)(xk + lane * 16);
      float4 X1 = *(const float4*)(xk + 1024 + lane * 16);
      bf16x8 ah, am, al;
      split8(X0, X1, ah, am, al);
#pragma unroll
      for (int f2 = 0; f2 < 2; ++f2) {
        acc[f2] = __builtin_amdgcn_mfma_f32_16x16x32_bf16(ah, Wf[ks][f2][0], acc[f2], 0, 0, 0);
        acc[f2] = __builtin_amdgcn_mfma_f32_16x16x32_bf16(ah, Wf[ks][f2][1], acc[f2], 0, 0, 0);
        acc[f2] = __builtin_amdgcn_mfma_f32_16x16x32_bf16(am, Wf[ks][f2][0], acc[f2], 0, 0, 0);
        acc[f2] = __builtin_amdgcn_mfma_f32_16x16x32_bf16(ah, Wf[ks][f2][2], acc[f2], 0, 0, 0);
        acc[f2] = __builtin_amdgcn_mfma_f32_16x16x32_bf16(al, Wf[ks][f2][0], acc[f2], 0, 0, 0);
        acc[f2] = __builtin_amdgcn_mfma_f32_16x16x32_bf16(am, Wf[ks][f2][1], acc[f2], 0, 0, 0);
      }
    }
    // scq[kq][tok][e]: C layout col(=e frag col)=lane&15, row=(lane>>4)*4+reg
#pragma unroll
    for (int f2 = 0; f2 < 2; ++f2) {
      int e = eh * 32 + f2 * 16 + (lane & 15);
      int tk = (lane >> 4) << 2;
#pragma unroll
      for (int r = 0; r < 4; ++r)
        scq[kq][tk + r][e] = acc[f2][r];
    }
    __builtin_amdgcn_s_barrier();
    asm volatile("" ::: "memory");
    if (wid < 4) {                      // 4-way k-quarter merge + store
#pragma unroll
      for (int i = 0; i < 4; ++i) {
        int t = wid * 4 + i;
        float v = scq[0][t][lane] + scq[1][t][lane]
                + scq[2][t][lane] + scq[3][t][lane];
        part[(size_t)(t0 + cc * XCH + t) * (NSL * NE) + slice * NE + lane] = v;
      }
    }
    // next iteration's vmcnt+barrier protects scq/x-buffer reuse
  }
#undef STAGE
}

// ---------------------------------------------------------------------------
// k2: sum 8 K-slice partials -> softmax -> top-8 -> stats -> finalize.
// Grid 256 x 512 thr; block = 64 tokens. Epilogue = r9/r13-verified code.
// ---------------------------------------------------------------------------
__global__ __launch_bounds__(512) void gate_k2(const float* __restrict__ part,
                                               float* __restrict__ out,
                                               float* __restrict__ ce,
                                               float* __restrict__ ssum,
                                               int* __restrict__ cnt) {
  __shared__ float sc[NE][65];
  __shared__ float hist[NE];
  __shared__ int lastflag;

  const int tid = threadIdx.x;
  const int bid = blockIdx.x;
  const int t0 = bid * 64;
  const int b = bid >> 6;               // 64 blocks per batch row
  if (tid < NE) hist[tid] = 0.f;

  const int t = tid >> 3;               // 0..63
  const int j = tid & 7;
  float p[8] = {0.f, 0.f, 0.f, 0.f, 0.f, 0.f, 0.f, 0.f};
  const float* pb = part + (size_t)(t0 + t) * (NSL * NE) + j * 8;
#pragma unroll
  for (int s = 0; s < NSL; ++s) {
    float4 a = *(const float4*)(pb + s * NE);
    float4 bq = *(const float4*)(pb + s * NE + 4);
    p[0] += a.x;  p[1] += a.y;  p[2] += a.z;  p[3] += a.w;
    p[4] += bq.x; p[5] += bq.y; p[6] += bq.z; p[7] += bq.w;
  }

  float m = p[0];
#pragma unroll
  for (int i = 1; i < 8; ++i) m = fmaxf(m, p[i]);
  m = fmaxf(m, __shfl_xor(m, 1, 8));
  m = fmaxf(m, __shfl_xor(m, 2, 8));
  m = fmaxf(m, __shfl_xor(m, 4, 8));
  float s = 0.f;
#pragma unroll
  for (int i = 0; i < 8; ++i) { p[i] = __expf(p[i] - m); s += p[i]; }
  s += __shfl_xor(s, 1, 8);
  s += __shfl_xor(s, 2, 8);
  s += __shfl_xor(s, 4, 8);
  float inv = 1.f / s;
#pragma unroll
  for (int i = 0; i < 8; ++i) { p[i] *= inv; sc[j * 8 + i][t] = p[i]; }
  __syncthreads();                      // hist init + sc visible

  unsigned used = 0;
  float wsum = 0.f;
  float wv[KTOP];
  int wi_[KTOP];
#pragma unroll
  for (int sel = 0; sel < KTOP; ++sel) {
    float bv = -1.f;
    int bi = 0;
#pragma unroll
    for (int i = 0; i < 8; ++i) {
      bool ok = !((used >> i) & 1u);
      if (ok && p[i] > bv) { bv = p[i]; bi = i; }
    }
    int ge = j * 8 + bi;
#pragma unroll
    for (int mk = 1; mk < 8; mk <<= 1) {
      float ov = __shfl_xor(bv, mk, 8);
      int og = __shfl_xor(ge, mk, 8);
      if (ov > bv || (ov == bv && og < ge)) { bv = ov; ge = og; }
    }
    if ((ge >> 3) == j) used |= 1u << (ge & 7);
    wv[sel] = bv;
    wi_[sel] = ge;
    wsum += bv;
  }
  if (j == 0) {
    float winv = 1.f / (wsum + 1e-20f);
#pragma unroll
    for (int sel = 0; sel < KTOP; ++sel) {
      out[(size_t)(t0 + t) * KTOP + sel] = (float)wi_[sel];
      out[(size_t)TOK * KTOP + (size_t)(t0 + t) * KTOP + sel] = wv[sel] * winv;
      atomicAdd(&hist[wi_[sel]], 1.f);
    }
  }
  __syncthreads();

  if (tid < NE) {
    float ssl = 0.f;
#pragma unroll
    for (int tt = 0; tt < 64; ++tt) ssl += sc[tid][tt];
    atomicAdd(&ssum[b * NE + tid], ssl);
    atomicAdd(&ce[b * NE + tid], hist[tid]);
  }

  __threadfence();
  __syncthreads();
  if (tid == 0) lastflag = (atomicAdd(cnt, 1) == (int)gridDim.x - 1);
  __syncthreads();
  if (lastflag && tid < 64) {
    const int e = tid;
    float loads = 0.f, aux = 0.f;
#pragma unroll
    for (int b2 = 0; b2 < NB; ++b2) {
      float cv = atomicAdd(&ce[b2 * 64 + e], 0.f);
      float sv = atomicAdd(&ssum[b2 * 64 + e], 0.f);
      loads += cv;
      aux += (cv / 512.0f) * (sv / 4096.0f);  // (S*K/E)=512, S=4096
    }
    out[(size_t)2 * TOK * KTOP + 1 + e] = loads;
#pragma unroll
    for (int off = 32; off > 0; off >>= 1) aux += __shfl_down(aux, off);
    if (e == 0) out[(size_t)2 * TOK * KTOP] = aux * (0.1f / 4.0f);  // ALPHA/B
  }
}

// ---------------------------------------------------------------------------
// FALLBACK (ws too small): r9-verified trio, 59 us.
// ---------------------------------------------------------------------------
__global__ __launch_bounds__(256, 2) void gate_fused_fb(const float* __restrict__ x,
                                                        const char* __restrict__ wpk,
                                                        float* __restrict__ out,
                                                        float* __restrict__ ce,
                                                        float* __restrict__ ssum) {
  __shared__ __align__(16) char lds[65536];
  __shared__ float hist[NE];

  const int tid = threadIdx.x;
  const int bid = blockIdx.x;
  const int t0 = bid * BTF;
  const int b = bid >> 7;
  const int lane = tid & 63;
  const int wid = tid >> 6;
  const int half = wid & 1;
  const int tg = (wid >> 1);

  if (tid < NE) hist[tid] = 0.f;

  const char* xsg[2];
  int xdo_[2];
#pragma unroll
  for (int r = 0; r < 2; ++r) {
    int s = r * 256 + tid;
    int stg = s >> 8, sks = (s >> 7) & 1, sq = (s >> 6) & 1, ln = s & 63;
    xsg[r] = (const char*)(x + (size_t)(t0 + stg * 16 + (ln & 15)) * HDIM
                           + sks * 32 + ((ln >> 4) << 3) + sq * 4);
    xdo_[r] = (r * 256 + wid * 64) * 16;
  }
  const char* wsrc = wpk + (size_t)lane * 16;
  f32x4 acc[2] = {{0.f, 0.f, 0.f, 0.f}, {0.f, 0.f, 0.f, 0.f}};

#define STAGEF(cc, sel)                                                       \
  {                                                                           \
    const char* wp_ = wsrc + (size_t)(cc) * 24576;                            \
    char* wd_ = lds + (sel) * 24576;                                          \
    _Pragma("unroll")                                                         \
    for (int i = 0; i < 6; ++i)                                               \
      gl_lds16(wp_ + (i * 4 + wid) * 1024, wd_ + (i * 4 + wid) * 1024);       \
    char* xdst = lds + 49152 + (sel) * 8192;                                  \
    _Pragma("unroll")                                                         \
    for (int r = 0; r < 2; ++r)                                               \
      gl_lds16(xsg[r] + (size_t)(cc) * 256, xdst + xdo_[r]);                  \
  }

  STAGEF(0, 0);
  asm volatile("s_waitcnt vmcnt(0)" ::: "memory");
  __builtin_amdgcn_s_barrier();
  asm volatile("" ::: "memory");

#pragma unroll 1
  for (int c = 0; c < NC; ++c) {
    const int sel = c & 1;
    if (c + 1 < NC) STAGEF(c + 1, sel ^ 1);
    char* wb = lds + sel * 24576;
    char* xb = lds + 49152 + sel * 8192 + tg * 4096;
#pragma unroll
    for (int ks = 0; ks < 2; ++ks) {
      float4 X0 = *(const float4*)(xb + ks * 2048 + lane * 16);
      float4 X1 = *(const float4*)(xb + ks * 2048 + 1024 + lane * 16);
      bf16x8 ah, am, al;
      split8(X0, X1, ah, am, al);
      const char* wk = wb + ks * 12288 + half * 6144 + lane * 16;
#pragma unroll
      for (int f2 = 0; f2 < 2; ++f2) {
        const char* bb = wk + f2 * 3072;
        bf16x8 bh = *(const bf16x8*)(bb);
        bf16x8 bm = *(const bf16x8*)(bb + 1024);
        bf16x8 bl = *(const bf16x8*)(bb + 2048);
        acc[f2] = __builtin_amdgcn_mfma_f32_16x16x32_bf16(ah, bh, acc[f2], 0, 0, 0);
        acc[f2] = __builtin_amdgcn_mfma_f32_16x16x32_bf16(ah, bm, acc[f2], 0, 0, 0);
        acc[f2] = __builtin_amdgcn_mfma_f32_16x16x32_bf16(am, bh, acc[f2], 0, 0, 0);
        acc[f2] = __builtin_amdgcn_mfma_f32_16x16x32_bf16(ah, bl, acc[f2], 0, 0, 0);
        acc[f2] = __builtin_amdgcn_mfma_f32_16x16x32_bf16(al, bh, acc[f2], 0, 0, 0);
        acc[f2] = __builtin_amdgcn_mfma_f32_16x16x32_bf16(am, bm, acc[f2], 0, 0, 0);
      }
    }
    asm volatile("s_waitcnt vmcnt(0)" ::: "memory");
    __builtin_amdgcn_s_barrier();
    asm volatile("" ::: "memory");
  }
#undef STAGEF

  float (*sc)[BTF + 1] = (float(*)[BTF + 1])lds;
#pragma unroll
  for (int f2 = 0; f2 < 2; ++f2) {
    int e = half * 32 + f2 * 16 + (lane & 15);
    int tk = tg * 16 + ((lane >> 4) << 2);
    sc[e][tk + 0] = acc[f2][0];
    sc[e][tk + 1] = acc[f2][1];
    sc[e][tk + 2] = acc[f2][2];
    sc[e][tk + 3] = acc[f2][3];
  }
  __syncthreads();

  const int t = tid >> 3;
  const int j = tid & 7;
  float p[8];
#pragma unroll
  for (int i = 0; i < 8; ++i) p[i] = sc[j * 8 + i][t];
  float m = p[0];
#pragma unroll
  for (int i = 1; i < 8; ++i) m = fmaxf(m, p[i]);
  m = fmaxf(m, __shfl_xor(m, 1, 8));
  m = fmaxf(m, __shfl_xor(m, 2, 8));
  m = fmaxf(m, __shfl_xor(m, 4, 8));
  float s = 0.f;
#pragma unroll
  for (int i = 0; i < 8; ++i) { p[i] = __expf(p[i] - m); s += p[i]; }
  s += __shfl_xor(s, 1, 8);
  s += __shfl_xor(s, 2, 8);
  s += __shfl_xor(s, 4, 8);
  float inv = 1.f / s;
#pragma unroll
  for (int i = 0; i < 8; ++i) { p[i] *= inv; sc[j * 8 + i][t] = p[i]; }

  unsigned used = 0;
  float wsum = 0.f;
  float wv[KTOP];
  int wi_[KTOP];
#pragma unroll
  for (int sel = 0; sel < KTOP; ++sel) {
    float bv = -1.f;
    int bi = 0;
#pragma unroll
    for (int i = 0; i < 8; ++i) {
      bool ok = !((used >> i) & 1u);
      if (ok && p[i] > bv) { bv = p[i]; bi = i; }
    }
    int ge = j * 8 + bi;
#pragma unroll
    for (int mk = 1; mk < 8; mk <<= 1) {
      float ov = __shfl_xor(bv, mk, 8);
      int og = __shfl_xor(ge, mk, 8);
      if (ov > bv || (ov == bv && og < ge)) { bv = ov; ge = og; }
    }
    if ((ge >> 3) == j) used |= 1u << (ge & 7);
    wv[sel] = bv;
    wi_[sel] = ge;
    wsum += bv;
  }
  if (j == 0) {
    float winv = 1.f / (wsum + 1e-20f);
#pragma unroll
    for (int sel = 0; sel < KTOP; ++sel) {
      out[(size_t)(t0 + t) * KTOP + sel] = (float)wi_[sel];
      out[(size_t)TOK * KTOP + (size_t)(t0 + t) * KTOP + sel] = wv[sel] * winv;
      atomicAdd(&hist[wi_[sel]], 1.f);
    }
  }
  __syncthreads();
  if (tid < NE) {
    float ssl = 0.f;
#pragma unroll
    for (int tt = 0; tt < BTF; ++tt) ssl += sc[tid][tt];
    atomicAdd(&ssum[b * NE + tid], ssl);
    atomicAdd(&ce[b * NE + tid], hist[tid]);
  }
}

__global__ __launch_bounds__(64) void gate_final(const float* __restrict__ ce,
                                                 const float* __restrict__ ssum,
                                                 float* __restrict__ out) {
  const int e = threadIdx.x;
  float loads = 0.f, aux = 0.f;
#pragma unroll
  for (int b = 0; b < NB; ++b) {
    float c = ce[b * 64 + e];
    loads += c;
    aux += (c / 512.0f) * (ssum[b * 64 + e] / 4096.0f);
  }
  out[(size_t)2 * TOK * KTOP + 1 + e] = loads;
#pragma unroll
  for (int off = 32; off > 0; off >>= 1) aux += __shfl_down(aux, off);
  if (e == 0) out[(size_t)2 * TOK * KTOP] = aux * (0.1f / 4.0f);
}

extern "C" void kernel_launch(void* const* d_in, const int* in_sizes, int n_in,
                              void* d_out, int out_size, void* d_ws, size_t ws_size,
                              hipStream_t stream) {
  const float* x = (const float*)d_in[0];
  const float* w = (const float*)d_in[1];
  float* out = (float*)d_out;

  char* wpk = (char*)d_ws;                          // 768 KB
  const size_t wpk_bytes = (size_t)NC * 24576;
  const size_t part_elems = (size_t)TOK * NSL * NE; // 8M floats = 32 MB
  const size_t need = wpk_bytes + part_elems * 4 + 4096;

  if (ws_size >= need) {
    float* part = (float*)(wpk + wpk_bytes);
    float* stats = part + part_elems;
    float* ce = stats;                  // [NB][NE]
    float* ssum = ce + NB * NE;         // [NB][NE]
    int* cnt = (int*)(ssum + NB * NE);
    wsplit<<<dim3(64), dim3(256), 0, stream>>>(w, wpk, stats);
    gate_k1<<<dim3(NSL * (TOK / TT)), dim3(512), 0, stream>>>(x, wpk, part);
    gate_k2<<<dim3(TOK / 64), dim3(512), 0, stream>>>(part, out, ce, ssum, cnt);
  } else {
    float* stats = (float*)(wpk + wpk_bytes);
    float* ce = stats;
    float* ssum = ce + NB * NE;
    wsplit<<<dim3(64), dim3(256), 0, stream>>>(w, wpk, stats);
    gate_fused_fb<<<dim3(TOK / BTF), dim3(256), 0, stream>>>(x, wpk, out, ce, ssum);
    gate_final<<<dim3(1), dim3(64), 0, stream>>>(ce, ssum, out);
  }
}

// Round 15
// 93.477 us; speedup vs baseline: 1.0250x; 1.0250x over previous
//
#include <hip/hip_runtime.h>
#include <hip/hip_bf16.h>
#include <math.h>

#define TOK 16384
#define HDIM 2048
#define NE 64
#define NB 4
#define KTOP 8
#define KC 64
#define NC (HDIM / KC)   // 32 chunks
#define BT 32            // tokens per block

typedef __attribute__((ext_vector_type(8))) __bf16 bf16x8;
typedef __attribute__((ext_vector_type(4))) float f32x4;
typedef unsigned int uint;

__device__ __forceinline__ uint asu(float f) { union { float f; uint u; } c; c.f = f; return c.u; }
__device__ __forceinline__ float asf(uint u) { union { uint u; float f; } c; c.u = u; return c.f; }

// Exact 3-way bf16 split: h+m+l == x bitwise (8 mantissa bits per plane).
__device__ __forceinline__ void split3(float v, uint& h, uint& m, uint& l) {
  uint u = asu(v);
  h = u & 0xffff0000u;
  float d = v - asf(h);
  m = asu(d) & 0xffff0000u;
  float d2 = d - asf(m);
  l = asu(d2);
}

// 8 floats (one fragment k-slot) -> 3 bf16x8 planes, in-register.
__device__ __forceinline__ void split8(float4 a, float4 b,
                                       bf16x8& h8, bf16x8& m8, bf16x8& l8) {
  union { uint4 u; bf16x8 v; } H, M, L;
  uint h0, m0, l0, h1, m1, l1;
  split3(a.x, h0, m0, l0); split3(a.y, h1, m1, l1);
  H.u.x = (h0 >> 16) | (h1 & 0xffff0000u);
  M.u.x = (m0 >> 16) | (m1 & 0xffff0000u);
  L.u.x = (l0 >> 16) | (l1 & 0xffff0000u);
  split3(a.z, h0, m0, l0); split3(a.w, h1, m1, l1);
  H.u.y = (h0 >> 16) | (h1 & 0xffff0000u);
  M.u.y = (m0 >> 16) | (m1 & 0xffff0000u);
  L.u.y = (l0 >> 16) | (l1 & 0xffff0000u);
  split3(b.x, h0, m0, l0); split3(b.y, h1, m1, l1);
  H.u.z = (h0 >> 16) | (h1 & 0xffff0000u);
  M.u.z = (m0 >> 16) | (m1 & 0xffff0000u);
  L.u.z = (l0 >> 16) | (l1 & 0xffff0000u);
  split3(b.z, h0, m0, l0); split3(b.w, h1, m1, l1);
  H.u.w = (h0 >> 16) | (h1 & 0xffff0000u);
  M.u.w = (m0 >> 16) | (m1 & 0xffff0000u);
  L.u.w = (l0 >> 16) | (l1 & 0xffff0000u);
  h8 = H.v; m8 = M.v; l8 = L.v;
}

__device__ __forceinline__ void gl_lds16(const void* g, void* l) {
  __builtin_amdgcn_global_load_lds(
      (const __attribute__((address_space(1))) void*)g,
      (__attribute__((address_space(3))) void*)l, 16, 0, 0);
}

// ---------------------------------------------------------------------------
// wsplit: pack W into 16x16x32 B-fragment order, 3 exact bf16 planes; zero
// ce/ssum/cnt (528 floats).
// byte = c*24576 + ks*12288 + half*6144 + f2*3072 + plane*1024 + lane*16
// Fragment (c,ks,half,f2,plane,lane): e = half*32+f2*16+(lane&15),
//                                     k = c*64+ks*32+(lane>>4)*8
// ---------------------------------------------------------------------------
__global__ __launch_bounds__(256) void wsplit(const float* __restrict__ w,
                                              char* __restrict__ wpk,
                                              float* __restrict__ stats) {
  if (blockIdx.x == 0 && threadIdx.x < 132) {
    *(float4*)(stats + threadIdx.x * 4) = make_float4(0.f, 0.f, 0.f, 0.f);
  }
  int t = blockIdx.x * 256 + threadIdx.x;    // 16384 threads
  int lane = t & 63;
  int f2 = (t >> 6) & 1, half = (t >> 7) & 1, ks = (t >> 8) & 1, c = t >> 9;
  int e = half * 32 + f2 * 16 + (lane & 15);
  int k = c * 64 + ks * 32 + ((lane >> 4) << 3);
  const float* p = w + (size_t)e * HDIM + k;
  bf16x8 h8, m8, l8;
  split8(*(const float4*)p, *(const float4*)(p + 4), h8, m8, l8);
  union { bf16x8 v; uint4 u; } H, M, L;
  H.v = h8; M.v = m8; L.v = l8;
  size_t base = (size_t)c * 24576 + (size_t)ks * 12288 + (size_t)half * 6144
              + (size_t)f2 * 3072 + (size_t)lane * 16;
  *(uint4*)(wpk + base) = H.u;
  *(uint4*)(wpk + base + 1024) = M.u;
  *(uint4*)(wpk + base + 2048) = L.u;
}

// ---------------------------------------------------------------------------
// Fused gate = r9 (best, 59.0 us) + two deltas:
//  (1) X staging slot permutation p = row*16 + (kgroup ^ row): each 16-lane
//      group's global sources are one row's CONTIGUOUS 256 B window
//      (16 cache lines / 1 KB instr vs r9's 32 = 2x L2-request reduction);
//      reader applies the same XOR (bank distribution identical to r9).
//      Same values, same MFMA order -> bitwise-identical logits.
//  (2) finalize merged in via completion counter (r10/r12/r13-proven),
//      wave-0 shfl broadcast (no extra LDS).
// 512 blocks x 256 thr (4 waves), 2 blocks/CU. Wave = 16 tok x 32 exp.
// LDS: W dbuf 2x24 KB @0, X dbuf 2x8 KB @49152.
// ---------------------------------------------------------------------------
__global__ __launch_bounds__(256, 2) void gate_fused(const float* __restrict__ x,
                                                     const char* __restrict__ wpk,
                                                     float* __restrict__ out,
                                                     float* __restrict__ ce,
                                                     float* __restrict__ ssum,
                                                     int* __restrict__ cnt) {
  __shared__ __align__(16) char lds[65536];   // [W0|W1|X0|X1]
  __shared__ float hist[NE];

  const int tid = threadIdx.x;
  const int bid = blockIdx.x;
  const int t0 = bid * BT;
  const int b = bid >> 7;                     // 128 blocks per batch row
  const int lane = tid & 63;
  const int wid = tid >> 6;                   // 0..3
  const int half = wid & 1;                   // expert half
  const int tg = (wid >> 1);                  // token group: 0 or 1

  if (tid < NE) hist[tid] = 0.f;

  // X staging, permuted slots (delta 1). Phys slot within r-block:
  //   p = wid*64 + lane;  row = p>>4 (= wid*4 + (lane>>4));  kg = (p&15)^row.
  // Content: x[t0 + r*16 + row][c*64 + kg*4 .. +3].
  // Source per 16-lane group = one row's contiguous 256 B window.
  const int row_l = wid * 4 + (lane >> 4);    // 0..15
  const int kg = (lane & 15) ^ row_l;         // permuted k-group
  const char* xsg[2];
  int xdo_[2];
#pragma unroll
  for (int r = 0; r < 2; ++r) {
    xsg[r] = (const char*)(x + (size_t)(t0 + r * 16 + row_l) * HDIM + kg * 4);
    xdo_[r] = (r * 256 + wid * 64) * 16;      // wave-uniform dest offset
  }
  const char* wsrc = wpk + (size_t)lane * 16;

  f32x4 acc[2] = {{0.f, 0.f, 0.f, 0.f}, {0.f, 0.f, 0.f, 0.f}};

#define STAGE(cc, sel)                                                        \
  {                                                                           \
    const char* wp_ = wsrc + (size_t)(cc) * 24576;                            \
    char* wd_ = lds + (sel) * 24576;                                          \
    _Pragma("unroll")                                                         \
    for (int i = 0; i < 6; ++i)                                               \
      gl_lds16(wp_ + (i * 4 + wid) * 1024, wd_ + (i * 4 + wid) * 1024);       \
    char* xdst = lds + 49152 + (sel) * 8192;                                  \
    _Pragma("unroll")                                                         \
    for (int r = 0; r < 2; ++r)                                               \
      gl_lds16(xsg[r] + (size_t)(cc) * 256, xdst + xdo_[r]);                  \
  }

  // ---- prologue: stage chunk 0, drain, barrier
  STAGE(0, 0);
  asm volatile("s_waitcnt vmcnt(0)" ::: "memory");
  __builtin_amdgcn_s_barrier();
  asm volatile("" ::: "memory");

  const int rr = lane & 15;                   // reader: content row
  const int gq = (lane >> 4) << 1;            // reader: kgroup base (even)

#pragma unroll 1
  for (int c = 0; c < NC; ++c) {
    const int sel = c & 1;
    if (c + 1 < NC) STAGE(c + 1, sel ^ 1);    // 1: stage next chunk (async)

    char* wb = lds + sel * 24576;
    char* xb = lds + 49152 + sel * 8192 + tg * 4096 + rr * 256;
#pragma unroll
    for (int ks = 0; ks < 2; ++ks) {          // 2: X from LDS, split, MFMA
      float4 X0 = *(const float4*)(xb + (((ks * 8 + gq + 0) ^ rr) << 4));
      float4 X1 = *(const float4*)(xb + (((ks * 8 + gq + 1) ^ rr) << 4));
      bf16x8 ah, am, al;
      split8(X0, X1, ah, am, al);
      const char* wk = wb + ks * 12288 + half * 6144 + lane * 16;
#pragma unroll
      for (int f2 = 0; f2 < 2; ++f2) {
        const char* bb = wk + f2 * 3072;
        bf16x8 bh = *(const bf16x8*)(bb);
        bf16x8 bm = *(const bf16x8*)(bb + 1024);
        bf16x8 bl = *(const bf16x8*)(bb + 2048);
        acc[f2] = __builtin_amdgcn_mfma_f32_16x16x32_bf16(ah, bh, acc[f2], 0, 0, 0);
        acc[f2] = __builtin_amdgcn_mfma_f32_16x16x32_bf16(ah, bm, acc[f2], 0, 0, 0);
        acc[f2] = __builtin_amdgcn_mfma_f32_16x16x32_bf16(am, bh, acc[f2], 0, 0, 0);
        acc[f2] = __builtin_amdgcn_mfma_f32_16x16x32_bf16(ah, bl, acc[f2], 0, 0, 0);
        acc[f2] = __builtin_amdgcn_mfma_f32_16x16x32_bf16(al, bh, acc[f2], 0, 0, 0);
        acc[f2] = __builtin_amdgcn_mfma_f32_16x16x32_bf16(am, bm, acc[f2], 0, 0, 0);
      }
    }
    // 3: drain the staging issued at top of THIS chunk; barrier
    asm volatile("s_waitcnt vmcnt(0)" ::: "memory");
    __builtin_amdgcn_s_barrier();
    asm volatile("" ::: "memory");
  }
#undef STAGE

  // C frags -> sc[expert][token]. C layout: col(=expert)=lane&15,
  // row(=token)=(lane>>4)*4+reg  [m89-verified]
  float (*sc)[BT + 1] = (float(*)[BT + 1])lds;
#pragma unroll
  for (int f2 = 0; f2 < 2; ++f2) {
    int e = half * 32 + f2 * 16 + (lane & 15);
    int tk = tg * 16 + ((lane >> 4) << 2);
    sc[e][tk + 0] = acc[f2][0];
    sc[e][tk + 1] = acc[f2][1];
    sc[e][tk + 2] = acc[f2][2];
    sc[e][tk + 3] = acc[f2][3];
  }
  __syncthreads();

  // softmax + top-8: 8 lanes per token (t = 0..31), 8 experts per lane
  const int t = tid >> 3;
  const int j = tid & 7;
  float p[8];
#pragma unroll
  for (int i = 0; i < 8; ++i) p[i] = sc[j * 8 + i][t];

  float m = p[0];
#pragma unroll
  for (int i = 1; i < 8; ++i) m = fmaxf(m, p[i]);
  m = fmaxf(m, __shfl_xor(m, 1, 8));
  m = fmaxf(m, __shfl_xor(m, 2, 8));
  m = fmaxf(m, __shfl_xor(m, 4, 8));
  float s = 0.f;
#pragma unroll
  for (int i = 0; i < 8; ++i) { p[i] = __expf(p[i] - m); s += p[i]; }
  s += __shfl_xor(s, 1, 8);
  s += __shfl_xor(s, 2, 8);
  s += __shfl_xor(s, 4, 8);
  float inv = 1.f / s;
#pragma unroll
  for (int i = 0; i < 8; ++i) { p[i] *= inv; sc[j * 8 + i][t] = p[i]; }

  // top-8: strict-> scan (lowest idx on tie), 8-lane (val,idx) reduce
  unsigned used = 0;
  float wsum = 0.f;
  float wv[KTOP];
  int wi_[KTOP];
#pragma unroll
  for (int sel = 0; sel < KTOP; ++sel) {
    float bv = -1.f;
    int bi = 0;
#pragma unroll
    for (int i = 0; i < 8; ++i) {
      bool ok = !((used >> i) & 1u);
      if (ok && p[i] > bv) { bv = p[i]; bi = i; }
    }
    int ge = j * 8 + bi;
#pragma unroll
    for (int mk = 1; mk < 8; mk <<= 1) {
      float ov = __shfl_xor(bv, mk, 8);
      int og = __shfl_xor(ge, mk, 8);
      if (ov > bv || (ov == bv && og < ge)) { bv = ov; ge = og; }
    }
    if ((ge >> 3) == j) used |= 1u << (ge & 7);
    wv[sel] = bv;
    wi_[sel] = ge;
    wsum += bv;
  }
  if (j == 0) {
    float winv = 1.f / (wsum + 1e-20f);
#pragma unroll
    for (int sel = 0; sel < KTOP; ++sel) {
      out[(size_t)(t0 + t) * KTOP + sel] = (float)wi_[sel];
      out[(size_t)TOK * KTOP + (size_t)(t0 + t) * KTOP + sel] = wv[sel] * winv;
      atomicAdd(&hist[wi_[sel]], 1.f);
    }
  }
  __syncthreads();

  if (tid < NE) {
    float ssl = 0.f;
#pragma unroll
    for (int tt = 0; tt < BT; ++tt) ssl += sc[tid][tt];
    atomicAdd(&ssum[b * NE + tid], ssl);
    atomicAdd(&ce[b * NE + tid], hist[tid]);
  }

  // ---- merged finalize (delta 2): last block computes loads + aux_loss.
  // Wave-0-only; flag broadcast via shfl (no LDS). ce/ssum read back through
  // atomicAdd(p, 0) -> coherent at the atomic point (r12/r13-proven).
  __threadfence();
  __syncthreads();
  if (wid == 0) {
    int flag = 0;
    if (lane == 0) flag = (atomicAdd(cnt, 1) == (int)gridDim.x - 1) ? 1 : 0;
    flag = __shfl(flag, 0);
    if (flag) {
      const int e = lane;
      float loads = 0.f, aux = 0.f;
#pragma unroll
      for (int b2 = 0; b2 < NB; ++b2) {
        float cv = atomicAdd(&ce[b2 * 64 + e], 0.f);
        float sv = atomicAdd(&ssum[b2 * 64 + e], 0.f);
        loads += cv;
        aux += (cv / 512.0f) * (sv / 4096.0f);  // (S*K/E)=512, S=4096
      }
      out[(size_t)2 * TOK * KTOP + 1 + e] = loads;
#pragma unroll
      for (int off = 32; off > 0; off >>= 1) aux += __shfl_down(aux, off);
      if (e == 0) out[(size_t)2 * TOK * KTOP] = aux * (0.1f / 4.0f);  // ALPHA/B
    }
  }
}

extern "C" void kernel_launch(void* const* d_in, const int* in_sizes, int n_in,
                              void* d_out, int out_size, void* d_ws, size_t ws_size,
                              hipStream_t stream) {
  const float* x = (const float*)d_in[0];
  const float* w = (const float*)d_in[1];
  float* out = (float*)d_out;

  char* wpk = (char*)d_ws;                          // 32 chunks x 24 KB = 768 KB
  float* ce = (float*)(wpk + (size_t)NC * 24576);   // [NB][NE]
  float* ssum = ce + NB * NE;                       // [NB][NE]
  int* cnt = (int*)(ssum + NB * NE);                // completion counter

  wsplit<<<dim3(64), dim3(256), 0, stream>>>(w, wpk, ce);
  gate_fused<<<dim3(TOK / BT), dim3(256), 0, stream>>>(x, wpk, out, ce, ssum, cnt);
}

// Round 16
// 58.652 us; speedup vs baseline: 1.6336x; 1.5938x over previous
//
#include <hip/hip_runtime.h>
#include <hip/hip_bf16.h>
#include <math.h>

#define TOK 16384
#define HDIM 2048
#define NE 64
#define NB 4
#define KTOP 8
#define KC 64
#define NC (HDIM / KC)   // 32 chunks
#define BT 32            // tokens per block

typedef __attribute__((ext_vector_type(8))) __bf16 bf16x8;
typedef __attribute__((ext_vector_type(4))) float f32x4;
typedef unsigned int uint;

__device__ __forceinline__ uint asu(float f) { union { float f; uint u; } c; c.f = f; return c.u; }
__device__ __forceinline__ float asf(uint u) { union { uint u; float f; } c; c.u = u; return c.f; }

// Exact 3-way bf16 split: h+m+l == x bitwise (8 mantissa bits per plane).
__device__ __forceinline__ void split3(float v, uint& h, uint& m, uint& l) {
  uint u = asu(v);
  h = u & 0xffff0000u;
  float d = v - asf(h);
  m = asu(d) & 0xffff0000u;
  float d2 = d - asf(m);
  l = asu(d2);
}

// 8 floats (one fragment k-slot) -> 3 bf16x8 planes, in-register.
__device__ __forceinline__ void split8(float4 a, float4 b,
                                       bf16x8& h8, bf16x8& m8, bf16x8& l8) {
  union { uint4 u; bf16x8 v; } H, M, L;
  uint h0, m0, l0, h1, m1, l1;
  split3(a.x, h0, m0, l0); split3(a.y, h1, m1, l1);
  H.u.x = (h0 >> 16) | (h1 & 0xffff0000u);
  M.u.x = (m0 >> 16) | (m1 & 0xffff0000u);
  L.u.x = (l0 >> 16) | (l1 & 0xffff0000u);
  split3(a.z, h0, m0, l0); split3(a.w, h1, m1, l1);
  H.u.y = (h0 >> 16) | (h1 & 0xffff0000u);
  M.u.y = (m0 >> 16) | (m1 & 0xffff0000u);
  L.u.y = (l0 >> 16) | (l1 & 0xffff0000u);
  split3(b.x, h0, m0, l0); split3(b.y, h1, m1, l1);
  H.u.z = (h0 >> 16) | (h1 & 0xffff0000u);
  M.u.z = (m0 >> 16) | (m1 & 0xffff0000u);
  L.u.z = (l0 >> 16) | (l1 & 0xffff0000u);
  split3(b.z, h0, m0, l0); split3(b.w, h1, m1, l1);
  H.u.w = (h0 >> 16) | (h1 & 0xffff0000u);
  M.u.w = (m0 >> 16) | (m1 & 0xffff0000u);
  L.u.w = (l0 >> 16) | (l1 & 0xffff0000u);
  h8 = H.v; m8 = M.v; l8 = L.v;
}

__device__ __forceinline__ void gl_lds16(const void* g, void* l) {
  __builtin_amdgcn_global_load_lds(
      (const __attribute__((address_space(1))) void*)g,
      (__attribute__((address_space(3))) void*)l, 16, 0, 0);
}

// ---------------------------------------------------------------------------
// wsplit: pack W into B-fragment order, 3 exact bf16 planes; zero ce/ssum.
// byte addr = c*24576 + ks*12288 + half*6144 + f2*3072 + plane*1024 + lane*16
// Fragment (c,ks,half,f2,plane,lane): e = half*32+f2*16+(lane&15),
//                                     k = c*64+ks*32+(lane>>4)*8
// ---------------------------------------------------------------------------
__global__ __launch_bounds__(256) void wsplit(const float* __restrict__ w,
                                              char* __restrict__ wpk,
                                              float* __restrict__ stats) {
  if (blockIdx.x == 0 && threadIdx.x < 128) {   // zero ce+ssum (512 floats)
    *(float4*)(stats + threadIdx.x * 4) = make_float4(0.f, 0.f, 0.f, 0.f);
  }
  int t = blockIdx.x * 256 + threadIdx.x;    // 16384 threads
  int lane = t & 63;
  int f2 = (t >> 6) & 1, half = (t >> 7) & 1, ks = (t >> 8) & 1, c = t >> 9;
  int e = half * 32 + f2 * 16 + (lane & 15);
  int k = c * 64 + ks * 32 + ((lane >> 4) << 3);
  const float* p = w + (size_t)e * HDIM + k;
  bf16x8 h8, m8, l8;
  split8(*(const float4*)p, *(const float4*)(p + 4), h8, m8, l8);
  union { bf16x8 v; uint4 u; } H, M, L;
  H.v = h8; M.v = m8; L.v = l8;
  size_t base = (size_t)c * 24576 + (size_t)ks * 12288 + (size_t)half * 6144
              + (size_t)f2 * 3072 + (size_t)lane * 16;
  *(uint4*)(wpk + base) = H.u;
  *(uint4*)(wpk + base + 1024) = M.u;
  *(uint4*)(wpk + base + 2048) = L.u;
}

// ---------------------------------------------------------------------------
// Fused gate (r9-exact, session best 59.0 us). 512 blocks x 256 thr (4 waves),
// 2 blocks/CU. Wave = 16 tokens x 32 experts (2 C-frags).
// K-loop has NO register global loads: X and W both staged via
// global_load_lds (X: per-lane fragment-swizzled source, m173 pattern).
// One s_waitcnt vmcnt(0) + s_barrier per chunk (2-phase: stage(c+1) at top,
// drain at bottom after a full chunk of compute).
// NO __threadfence in this kernel: the r10/r12/r13/r15 ~35us regression
// tracks the merged-finalize threadfence (per-block L2 maintenance x512);
// the separate gate_final kernel gets coherence free at the launch boundary.
// LDS: W dbuf 2x24KB @0, X dbuf 2x8KB @49152. 64KB total -> 2 blocks/CU.
// X slot s (0..511) = [tg(1b)][ks(1b)][q(1b)][lane(6b)] holds
//   x[token = t0+tg*16+(lane&15)][k = c*64+ks*32+(lane>>4)*8+q*4 ..+3]
// -> readback: lane reads its own slot at lane*16: conflict-free b128.
// ---------------------------------------------------------------------------
__global__ __launch_bounds__(256, 2) void gate_fused(const float* __restrict__ x,
                                                     const char* __restrict__ wpk,
                                                     float* __restrict__ out,
                                                     float* __restrict__ ce,
                                                     float* __restrict__ ssum) {
  __shared__ __align__(16) char lds[65536];   // [W0|W1|X0|X1]
  __shared__ float hist[NE];

  const int tid = threadIdx.x;
  const int bid = blockIdx.x;
  const int t0 = bid * BT;
  const int b = bid >> 7;                     // 128 blocks per batch row
  const int lane = tid & 63;
  const int wid = tid >> 6;                   // 0..3
  const int half = wid & 1;                   // expert half
  const int tg = (wid >> 1);                  // token group: 0 or 1

  if (tid < NE) hist[tid] = 0.f;

  // X staging: 2 slots per thread, s = r*256 + tid. Source is per-lane
  // (fragment-swizzled); dest base is wave-uniform (s>>6 constant per wave).
  const char* xsg[2];
  int xdo_[2];
#pragma unroll
  for (int r = 0; r < 2; ++r) {
    int s = r * 256 + tid;
    int stg = s >> 8, sks = (s >> 7) & 1, sq = (s >> 6) & 1, ln = s & 63;
    xsg[r] = (const char*)(x + (size_t)(t0 + stg * 16 + (ln & 15)) * HDIM
                           + sks * 32 + ((ln >> 4) << 3) + sq * 4);
    xdo_[r] = (r * 256 + wid * 64) * 16;      // wave-uniform dest offset
  }
  const char* wsrc = wpk + (size_t)lane * 16;

  f32x4 acc[2] = {{0.f, 0.f, 0.f, 0.f}, {0.f, 0.f, 0.f, 0.f}};

#define STAGE(cc, sel)                                                        \
  {                                                                           \
    char* wdst = lds + (sel) * 24576;                                         \
    const char* wp_ = wsrc + (size_t)(cc) * 24576;                            \
    _Pragma("unroll")                                                         \
    for (int i = 0; i < 6; ++i)                                               \
      gl_lds16(wp_ + (i * 4 + wid) * 1024, wdst + (i * 4 + wid) * 1024);      \
    char* xdst = lds + 49152 + (sel) * 8192;                                  \
    _Pragma("unroll")                                                         \
    for (int r = 0; r < 2; ++r)                                               \
      gl_lds16(xsg[r] + (size_t)(cc) * 256, xdst + xdo_[r]);                  \
  }

  // ---- prologue: stage chunk 0, drain, barrier
  STAGE(0, 0);
  asm volatile("s_waitcnt vmcnt(0)" ::: "memory");
  __builtin_amdgcn_s_barrier();
  asm volatile("" ::: "memory");

#pragma unroll 1
  for (int c = 0; c < NC; ++c) {
    const int sel = c & 1;
    if (c + 1 < NC) STAGE(c + 1, sel ^ 1);    // 1: stage next chunk (async)

    char* wb = lds + sel * 24576;
    char* xb = lds + 49152 + sel * 8192 + tg * 4096;
#pragma unroll
    for (int ks = 0; ks < 2; ++ks) {          // 2: X from LDS, split, MFMA
      float4 X0 = *(const float4*)(xb + ks * 2048 + lane * 16);
      float4 X1 = *(const float4*)(xb + ks * 2048 + 1024 + lane * 16);
      bf16x8 ah, am, al;
      split8(X0, X1, ah, am, al);
      const char* wk = wb + ks * 12288 + half * 6144 + lane * 16;
#pragma unroll
      for (int f2 = 0; f2 < 2; ++f2) {
        const char* bb = wk + f2 * 3072;
        bf16x8 bh = *(const bf16x8*)(bb);
        bf16x8 bm = *(const bf16x8*)(bb + 1024);
        bf16x8 bl = *(const bf16x8*)(bb + 2048);
        acc[f2] = __builtin_amdgcn_mfma_f32_16x16x32_bf16(ah, bh, acc[f2], 0, 0, 0);
        acc[f2] = __builtin_amdgcn_mfma_f32_16x16x32_bf16(ah, bm, acc[f2], 0, 0, 0);
        acc[f2] = __builtin_amdgcn_mfma_f32_16x16x32_bf16(am, bh, acc[f2], 0, 0, 0);
        acc[f2] = __builtin_amdgcn_mfma_f32_16x16x32_bf16(ah, bl, acc[f2], 0, 0, 0);
        acc[f2] = __builtin_amdgcn_mfma_f32_16x16x32_bf16(al, bh, acc[f2], 0, 0, 0);
        acc[f2] = __builtin_amdgcn_mfma_f32_16x16x32_bf16(am, bm, acc[f2], 0, 0, 0);
      }
    }
    // 3: drain the staging issued at top of THIS chunk (full chunk in flight)
    asm volatile("s_waitcnt vmcnt(0)" ::: "memory");
    __builtin_amdgcn_s_barrier();
    asm volatile("" ::: "memory");
  }
#undef STAGE

  // C frags -> sc[expert][token]. C layout: col(=expert)=lane&15,
  // row(=token)=(lane>>4)*4+reg  [m89-verified]
  float (*sc)[BT + 1] = (float(*)[BT + 1])lds;
#pragma unroll
  for (int f2 = 0; f2 < 2; ++f2) {
    int e = half * 32 + f2 * 16 + (lane & 15);
    int tk = tg * 16 + ((lane >> 4) << 2);
    sc[e][tk + 0] = acc[f2][0];
    sc[e][tk + 1] = acc[f2][1];
    sc[e][tk + 2] = acc[f2][2];
    sc[e][tk + 3] = acc[f2][3];
  }
  __syncthreads();

  // softmax + top-8: 8 lanes per token (t = 0..31), 8 experts per lane
  const int t = tid >> 3;
  const int j = tid & 7;
  float p[8];
#pragma unroll
  for (int i = 0; i < 8; ++i) p[i] = sc[j * 8 + i][t];

  float m = p[0];
#pragma unroll
  for (int i = 1; i < 8; ++i) m = fmaxf(m, p[i]);
  m = fmaxf(m, __shfl_xor(m, 1, 8));
  m = fmaxf(m, __shfl_xor(m, 2, 8));
  m = fmaxf(m, __shfl_xor(m, 4, 8));
  float s = 0.f;
#pragma unroll
  for (int i = 0; i < 8; ++i) { p[i] = __expf(p[i] - m); s += p[i]; }
  s += __shfl_xor(s, 1, 8);
  s += __shfl_xor(s, 2, 8);
  s += __shfl_xor(s, 4, 8);
  float inv = 1.f / s;
#pragma unroll
  for (int i = 0; i < 8; ++i) { p[i] *= inv; sc[j * 8 + i][t] = p[i]; }

  // top-8: strict-> scan (lowest idx on tie), 8-lane (val,idx) reduce
  unsigned used = 0;
  float wsum = 0.f;
  float wv[KTOP];
  int wi_[KTOP];
#pragma unroll
  for (int sel = 0; sel < KTOP; ++sel) {
    float bv = -1.f;
    int bi = 0;
#pragma unroll
    for (int i = 0; i < 8; ++i) {
      bool ok = !((used >> i) & 1u);
      if (ok && p[i] > bv) { bv = p[i]; bi = i; }
    }
    int ge = j * 8 + bi;
#pragma unroll
    for (int mk = 1; mk < 8; mk <<= 1) {
      float ov = __shfl_xor(bv, mk, 8);
      int og = __shfl_xor(ge, mk, 8);
      if (ov > bv || (ov == bv && og < ge)) { bv = ov; ge = og; }
    }
    if ((ge >> 3) == j) used |= 1u << (ge & 7);
    wv[sel] = bv;
    wi_[sel] = ge;
    wsum += bv;
  }
  if (j == 0) {
    float winv = 1.f / (wsum + 1e-20f);
#pragma unroll
    for (int sel = 0; sel < KTOP; ++sel) {
      out[(size_t)(t0 + t) * KTOP + sel] = (float)wi_[sel];
      out[(size_t)TOK * KTOP + (size_t)(t0 + t) * KTOP + sel] = wv[sel] * winv;
      atomicAdd(&hist[wi_[sel]], 1.f);
    }
  }
  __syncthreads();

  if (tid < NE) {
    float ssl = 0.f;
#pragma unroll
    for (int tt = 0; tt < BT; ++tt) ssl += sc[tid][tt];
    atomicAdd(&ssum[b * NE + tid], ssl);
    atomicAdd(&ce[b * NE + tid], hist[tid]);
  }
}

// ---------------------------------------------------------------------------
// Finalize expert_loads + aux_loss (separate kernel: kernel boundary gives
// cross-XCD coherence once, instead of 512 per-block threadfences).
// ---------------------------------------------------------------------------
__global__ __launch_bounds__(64) void gate_final(const float* __restrict__ ce,
                                                 const float* __restrict__ ssum,
                                                 float* __restrict__ out) {
  const int e = threadIdx.x;
  float loads = 0.f, aux = 0.f;
#pragma unroll
  for (int b = 0; b < NB; ++b) {
    float c = ce[b * 64 + e];
    loads += c;
    aux += (c / 512.0f) * (ssum[b * 64 + e] / 4096.0f);  // (S*K/E)=512, S=4096
  }
  out[(size_t)2 * TOK * KTOP + 1 + e] = loads;
#pragma unroll
  for (int off = 32; off > 0; off >>= 1) aux += __shfl_down(aux, off);
  if (e == 0) out[(size_t)2 * TOK * KTOP] = aux * (0.1f / 4.0f);  // ALPHA/B
}

extern "C" void kernel_launch(void* const* d_in, const int* in_sizes, int n_in,
                              void* d_out, int out_size, void* d_ws, size_t ws_size,
                              hipStream_t stream) {
  const float* x = (const float*)d_in[0];
  const float* w = (const float*)d_in[1];
  float* out = (float*)d_out;

  char* wpk = (char*)d_ws;                         // 32 chunks x 24 KB = 768 KB
  float* ce = (float*)(wpk + (size_t)NC * 24576);  // [NB][NE]
  float* ssum = ce + NB * NE;                      // [NB][NE]

  wsplit<<<dim3(64), dim3(256), 0, stream>>>(w, wpk, ce);
  gate_fused<<<dim3(TOK / BT), dim3(256), 0, stream>>>(x, wpk, out, ce, ssum);
  gate_final<<<dim3(1), dim3(64), 0, stream>>>(ce, ssum, out);
}